// Round 15
// baseline (204.602 us; speedup 1.0000x reference)
//
#include <hip/hip_runtime.h>
#include <math.h>

#define NEG 0.2f
#define EPSV 1e-5f
#define LOG2E   1.44269504088896f
#define LN2     0.69314718055995f

typedef _Float16 v8h __attribute__((ext_vector_type(8)));
typedef _Float16 v4h __attribute__((ext_vector_type(4)));
typedef _Float16 v2h __attribute__((ext_vector_type(2)));
typedef __fp16   f16x2 __attribute__((ext_vector_type(2)));
typedef float    v4f __attribute__((ext_vector_type(4)));

__device__ __forceinline__ float lrelu(float v) { return fmaxf(v, NEG * v); }
__device__ __forceinline__ v4f lrelu4(v4f v) {
    return __builtin_elementwise_max(v, v * NEG);
}
__device__ __forceinline__ v2h lreluh2(v2h v) {
    return __builtin_elementwise_max(v, v * (_Float16)NEG);
}

// single-instruction exp2 (v_exp_f32); libm exp2f adds fixup code (R26 lesson)
__device__ __forceinline__ float fexp2(float x) {
#if __has_builtin(__builtin_amdgcn_exp2f)
    return __builtin_amdgcn_exp2f(x);
#else
    float r; asm("v_exp_f32 %0, %1" : "=v"(r) : "v"(x)); return r;
#endif
}

// cvt_pkrtz returns __fp16x2; bit-cast to _Float16x2 (same layout)
__device__ __forceinline__ v2h pk(float a, float b) {
    union { f16x2 i; v2h o; } u;
    u.i = __builtin_amdgcn_cvt_pkrtz(a, b);
    return u.o;
}

#define MFMA32(a, b, c) __builtin_amdgcn_mfma_f32_16x16x32_f16((a), (b), (c), 0, 0, 0)
#define MFMA16(a, b, c) __builtin_amdgcn_mfma_f32_16x16x16f16((a), (b), (c), 0, 0, 0)

// Round 28: register-domain produce-ahead pipelining. Evidence: R25 (halved
// serial length) flat; R27 (-7% VALU instr) flat with VALUBusy dropping ->
// the kernel is STALL-bound on the per-iteration chain (hidden MFMA latency
// + MFMA->VALU pack hazard sit on the critical path every iter), and
// occupancy is pinned at 4 waves/SIMD by the unified reg file.
// Fix: at iteration top, pack LAST iteration's raw hidden MFMA outputs
// (matured during consume -> no hazard wait), then issue hidden MFMAs for
// the NEXT iteration, then consume. Hidden latency overlaps consume.
// Cost: +26 live regs (php[4]/ahp/ghp raw + xv dup) -> est ~84 arch + 48
// acc, inside (256,4). Tripwire: WRITE > 17MB = spill -> revert.
// Base = R27 (log2e-folded weights, raw exp2, col-packed 8pt x 2k).
__global__ __launch_bounds__(256, 4)
void gsl_mfma(const float* __restrict__ x,
              const float* __restrict__ trans_w, const float* __restrict__ trans_g,
              const float* __restrict__ trans_b, const float* __restrict__ trans_m,
              const float* __restrict__ trans_v,
              const float* __restrict__ pos_w1, const float* __restrict__ pos_g,
              const float* __restrict__ pos_b, const float* __restrict__ pos_m,
              const float* __restrict__ pos_v, const float* __restrict__ pos_w2,
              const float* __restrict__ pos_b2,
              const float* __restrict__ gate_w1, const float* __restrict__ gate_g,
              const float* __restrict__ gate_b, const float* __restrict__ gate_m,
              const float* __restrict__ gate_v, const float* __restrict__ gate_w2,
              const float* __restrict__ gate_b2,
              const float* __restrict__ attn_w1, const float* __restrict__ attn_g,
              const float* __restrict__ attn_b, const float* __restrict__ attn_m,
              const float* __restrict__ attn_v, const float* __restrict__ attn_w2,
              const float* __restrict__ attn_b2,
              float* __restrict__ out)
{
    __shared__ _Float16 WHL[1536];  // 6 sets x 64 lanes x v4h (lane-linear)
                                    // sets 0-3: WP1 mt, 4: WA1, 5: WG1
    __shared__ _Float16 W2L[4096];  // 8 tiles x 64 lanes x v8h (lane-linear)
    __shared__ float    PB2[64];

    const int tid  = threadIdx.x;
    const int wv   = tid >> 6;
    const int lane = tid & 63;
    const int p    = lane & 15;
    const int q    = lane >> 4;

    const int pt   = p & 7;     // point slot within wave
    const int ksub = p >> 3;    // k sub-slot: lane's k = 2g + ksub

    const int b  = blockIdx.x >> 8;                       // 2048 blocks
    const int nb = (blockIdx.x & 255) << 5;               // 32 points/block
    const int n  = nb | (wv << 3) | pt;

    // ---- stage pos_w2 K=32 A-frags into W2L (lane-linear, x LOG2E) ----
    #pragma unroll
    for (int e = 0; e < 16; ++e) {
        int idx = tid * 16 + e;              // 4096 elements
        int t   = idx >> 9;
        int rem = idx & 511;
        int l   = rem >> 3;
        int j   = rem & 7;
        int qk  = l >> 4;
        int pp  = l & 15;
        int hl  = (j < 4) ? (4 * qk + j) : (16 + 4 * qk + (j - 4));
        W2L[t * 512 + l * 8 + j] = (_Float16)(LOG2E *
            pos_w2[((t >> 1) * 16 + pp) * 64 + (t & 1) * 32 + hl]);
    }

    // ---- stage produce-side weight A-frags into WHL (UNSCALED) ----
    if (tid < 64) {
        const int c = tid;                   // pos hidden channel
        float sp = pos_g[c] * rsqrtf(pos_v[c] + EPSV);
        float bp = pos_b[c] - pos_m[c] * sp;
        const int mt = c >> 4, pp = c & 15;
        for (int k = 0; k < 16; ++k) {
            float v = (k >= 3 && k < 6) ? pos_w1[c * 3 + (k - 3)] * sp
                                        : ((k == 6) ? bp : 0.f);
            WHL[mt * 256 + ((k >> 2) * 16 + pp) * 4 + (k & 3)] = (_Float16)v;
        }
        PB2[c] = pos_b2[c] * LOG2E;
    } else if (tid < 80) {
        const int j = tid - 64;              // attn hidden channel
        float sa = attn_g[j] * rsqrtf(attn_v[j] + EPSV);
        float ba = attn_b[j] - attn_m[j] * sa;
        for (int k = 0; k < 16; ++k) {
            float v = (k < 6) ? attn_w1[j * 6 + k] * sa : ((k == 6) ? ba : 0.f);
            WHL[1024 + ((k >> 2) * 16 + j) * 4 + (k & 3)] = (_Float16)v;
        }
    } else if (tid < 96) {
        const int j = tid - 80;              // gate hidden channel
        float sg = gate_g[j] * rsqrtf(gate_v[j] + EPSV);
        float bg = gate_b[j] - gate_m[j] * sg;
        for (int k = 0; k < 16; ++k) {
            float v = (k < 6) ? gate_w1[j * 6 + k] * sg : ((k == 6) ? bg : 0.f);
            WHL[1280 + ((k >> 2) * 16 + j) * 4 + (k & 3)] = (_Float16)v;
        }
    }

    // ---- persistent A-frags (consume-side: x LOG2E) ----
    v4h WTf[4], WA2f[4], WG2f;
    #pragma unroll
    for (int mt = 0; mt < 4; ++mt) {
        const int ch = mt * 16 + p;
        #pragma unroll
        for (int i = 0; i < 4; ++i)
            WA2f[mt][i] = (_Float16)(LOG2E * attn_w2[ch * 16 + q * 4 + i]);
        float st = trans_g[ch] * rsqrtf(trans_v[ch] + EPSV);
        float bt = trans_b[ch] - trans_m[ch] * st;
        #pragma unroll
        for (int i = 0; i < 4; ++i) {
            int k = q * 4 + i;
            float v = (k < 6) ? trans_w[ch * 6 + k] * st : ((k == 6) ? bt : 0.f);
            WTf[mt][i] = (_Float16)(LOG2E * v);
        }
    }
    #pragma unroll
    for (int i = 0; i < 4; ++i)
        WG2f[i] = (_Float16)(LOG2E * gate_w2[4 * q + i]);
    const float gb2v = gate_b2[0] * LOG2E;

    __syncthreads();   // W2L/WHL/PB2 visible to all waves

    const _Float16* const WHLp = WHL + lane * 4;   // + set*256
    const _Float16* const W2Lp = W2L + lane * 8;   // + tile*512
    const float* const    PB2p = PB2 + 4 * q;      // + mt*16

    const v4f zero = {0.f, 0.f, 0.f, 0.f};
    v4f den[4], num[4], cmx[4];
    #pragma unroll
    for (int mt = 0; mt < 4; ++mt) {
        den[mt] = zero; num[mt] = zero;
        cmx[mt] = (v4f){-3.4e38f, -3.4e38f, -3.4e38f, -3.4e38f};
    }

    // ---- per-lane channel streams (only the 4 this lane consumes) ----
    const float* xb = x + ((size_t)(b * 6) * 8192 + n) * 20;
    const int hi = q & 1;   // q>=2 dups q&1 (A-side k>=8 rows are zero)
    const float* const s0p = xb + (size_t)(hi ? 4 : 0) * 163840;
    const float* const s1p = xb + (size_t)(hi ? 5 : 1) * 163840;
    const float* const s2p = xb + (size_t)(hi ? 4 : 2) * 163840;  // hi: L1 dup
    const float* const s3p = xb + (size_t)(hi ? 5 : 3) * 163840;  // hi: L1 dup

    // build v4h B-frag; hi lanes' high half is the constant (1.0, 0.0)
    auto mk = [&](float a, float bb, float cc, float dd) -> v4h {
        v2h lo = pk(a, bb);
        v2h hh = pk(cc, dd);
        if (hi) { union { unsigned u; v2h h; } t; t.u = 0x00003C00u; hh = t.h; }
        return (v4h){lo.x, lo.y, hh.x, hh.y};
    };

    // ---- pipelined state: raw hidden MFMA outputs for the CURRENT iter ----
    v4f php[4], ahp, ghp;
    v4h xv_cur;

    // prologue: k = ksub
    float c0 = s0p[ksub], c1 = s1p[ksub], c2 = s2p[ksub], c3 = s3p[ksub];
    xv_cur = mk(c0, c1, c2, c3);
    #pragma unroll
    for (int mt = 0; mt < 4; ++mt)
        php[mt] = MFMA16(*(const v4h*)(WHLp + mt * 256), xv_cur, zero);
    ahp = MFMA16(*(const v4h*)(WHLp + 1024), xv_cur, zero);
    ghp = MFMA16(*(const v4h*)(WHLp + 1280), xv_cur, zero);
    c0 = s0p[2 + ksub]; c1 = s1p[2 + ksub];
    c2 = s2p[2 + ksub]; c3 = s3p[2 + ksub];

    #pragma unroll 1
    for (int g = 0; g < 10; ++g) {
        // prevent LICM from hoisting in-loop LDS reads into registers
        asm volatile("" ::: "memory");

        // ---- pack hidden(g): results matured during consume(g-1) ----
        union { v8h v; v4h h[2]; } uA, uC;   // tiles 0|1 and 2|3 concatenated
        #pragma unroll
        for (int mt = 0; mt < 4; ++mt) {
            v2h e0 = lreluh2(pk(php[mt][0], php[mt][1]));
            v2h e1 = lreluh2(pk(php[mt][2], php[mt][3]));
            v4h pkd = (v4h){e0.x, e0.y, e1.x, e1.y};
            if (mt < 2) uA.h[mt] = pkd; else uC.h[mt - 2] = pkd;
        }
        union { v4h v; v2h h[2]; } ua;
        ua.h[0] = lreluh2(pk(ahp[0], ahp[1]));
        ua.h[1] = lreluh2(pk(ahp[2], ahp[3]));
        const v4h ahB = ua.v;
        union { v4h v; v2h h[2]; } ug;
        ug.h[0] = lreluh2(pk(ghp[0], ghp[1]));
        ug.h[1] = lreluh2(pk(ghp[2], ghp[3]));
        v4f gav = MFMA16(WG2f, ug.v, zero);

        const v4h xv_use = xv_cur;

        // ---- produce hidden(g+1): latency overlaps consume(g) ----
        if (g < 9) {
            xv_cur = mk(c0, c1, c2, c3);
            if (g < 8) {
                const int kn = 2 * (g + 2) + ksub;
                c0 = s0p[kn]; c1 = s1p[kn]; c2 = s2p[kn]; c3 = s3p[kn];
            }
            #pragma unroll
            for (int mt = 0; mt < 4; ++mt)
                php[mt] = MFMA16(*(const v4h*)(WHLp + mt * 256), xv_cur, zero);
            ahp = MFMA16(*(const v4h*)(WHLp + 1024), xv_cur, zero);
            ghp = MFMA16(*(const v4h*)(WHLp + 1280), xv_cur, zero);
        }

        const float gate =
            __builtin_amdgcn_rcpf(1.f + fexp2(-(gav[0] + gb2v)));

        // ---- consume(g): everything in s = log2e scale ----
        #pragma unroll
        for (int mt = 0; mt < 4; ++mt) {
            v8h w2a = *(const v8h*)(W2Lp + (mt * 2 + 0) * 512);  // h 0..31
            v8h w2b = *(const v8h*)(W2Lp + (mt * 2 + 1) * 512);  // h 32..63
            v4f pe = MFMA32(w2a, uA.v, *(const v4f*)(PB2p + mt * 16));
            pe = MFMA32(w2b, uC.v, pe);
            v4f tfa = MFMA16(WTf[mt], xv_use, zero);
            v4f tfv = lrelu4(tfa) + pe;          // = s * true tfv
            pe = MFMA16(WA2f[mt], ahB, pe);      // = s * true logits
            v4f e;
            #pragma unroll
            for (int r = 0; r < 4; ++r) e[r] = fexp2(pe[r]);   // 1x v_exp_f32
            den[mt] += e;
            num[mt] += tfv * e;
            cmx[mt] = __builtin_elementwise_max(cmx[mt], tfv * gate);
        }
    }

    // ---- combine the two k sub-slots (lanes differing in bit 3 of p) ----
    #pragma unroll
    for (int mt = 0; mt < 4; ++mt) {
        #pragma unroll
        for (int r = 0; r < 4; ++r) {
            den[mt][r] += __shfl_xor(den[mt][r], 8);
            num[mt][r] += __shfl_xor(num[mt][r], 8);
            cmx[mt][r] = fmaxf(cmx[mt][r], __shfl_xor(cmx[mt][r], 8));
        }
    }

    // write out (unscale by ln2): ksub==0 lanes own ch mt*16+4q+r, point n
    if ((lane & 8) == 0) {
        #pragma unroll
        for (int mt = 0; mt < 4; ++mt) {
            #pragma unroll
            for (int r = 0; r < 4; ++r) {
                const int ch = mt * 16 + 4 * q + r;
                out[((size_t)(b * 64 + ch)) * 8192 + n] =
                    (num[mt][r] / den[mt][r] + cmx[mt][r]) * LN2;
            }
        }
    }
}

extern "C" void kernel_launch(void* const* d_in, const int* in_sizes, int n_in,
                              void* d_out, int out_size, void* d_ws, size_t ws_size,
                              hipStream_t stream) {
    const float* x       = (const float*)d_in[0];
    const float* trans_w = (const float*)d_in[1];
    const float* trans_g = (const float*)d_in[2];
    const float* trans_b = (const float*)d_in[3];
    const float* trans_m = (const float*)d_in[4];
    const float* trans_v = (const float*)d_in[5];
    const float* pos_w1  = (const float*)d_in[6];
    const float* pos_g   = (const float*)d_in[7];
    const float* pos_b   = (const float*)d_in[8];
    const float* pos_m   = (const float*)d_in[9];
    const float* pos_v   = (const float*)d_in[10];
    const float* pos_w2  = (const float*)d_in[11];
    const float* pos_b2  = (const float*)d_in[12];
    const float* gate_w1 = (const float*)d_in[13];
    const float* gate_g  = (const float*)d_in[14];
    const float* gate_b  = (const float*)d_in[15];
    const float* gate_m  = (const float*)d_in[16];
    const float* gate_v  = (const float*)d_in[17];
    const float* gate_w2 = (const float*)d_in[18];
    const float* gate_b2 = (const float*)d_in[19];
    const float* attn_w1 = (const float*)d_in[20];
    const float* attn_g  = (const float*)d_in[21];
    const float* attn_b  = (const float*)d_in[22];
    const float* attn_m  = (const float*)d_in[23];
    const float* attn_v  = (const float*)d_in[24];
    const float* attn_w2 = (const float*)d_in[25];
    const float* attn_b2 = (const float*)d_in[26];
    float* out = (float*)d_out;

    // 8 b * 256 blocks/b; block = 4 waves x (8 points x 2 k-slots)
    gsl_mfma<<<2048, 256, 0, stream>>>(
        x, trans_w, trans_g, trans_b, trans_m, trans_v,
        pos_w1, pos_g, pos_b, pos_m, pos_v, pos_w2, pos_b2,
        gate_w1, gate_g, gate_b, gate_m, gate_v, gate_w2, gate_b2,
        attn_w1, attn_g, attn_b, attn_m, attn_v, attn_w2, attn_b2,
        out);
}

// Round 16
// 170.666 us; speedup vs baseline: 1.1988x; 1.1988x over previous
//
#include <hip/hip_runtime.h>
#include <math.h>

#define NEG 0.2f
#define EPSV 1e-5f
#define LOG2E   1.44269504088896f
#define LN2     0.69314718055995f

typedef _Float16 v8h __attribute__((ext_vector_type(8)));
typedef _Float16 v4h __attribute__((ext_vector_type(4)));
typedef _Float16 v2h __attribute__((ext_vector_type(2)));
typedef __fp16   f16x2 __attribute__((ext_vector_type(2)));
typedef float    v4f __attribute__((ext_vector_type(4)));

__device__ __forceinline__ float lrelu(float v) { return fmaxf(v, NEG * v); }
__device__ __forceinline__ v4f lrelu4(v4f v) {
    return __builtin_elementwise_max(v, v * NEG);
}
__device__ __forceinline__ v2h lreluh2(v2h v) {
    return __builtin_elementwise_max(v, v * (_Float16)NEG);
}

// single-instruction exp2 (v_exp_f32); libm exp2f adds fixup code (R26 lesson)
__device__ __forceinline__ float fexp2(float x) {
#if __has_builtin(__builtin_amdgcn_exp2f)
    return __builtin_amdgcn_exp2f(x);
#else
    float r; asm("v_exp_f32 %0, %1" : "=v"(r) : "v"(x)); return r;
#endif
}

// cvt_pkrtz returns __fp16x2; bit-cast to _Float16x2 (same layout)
__device__ __forceinline__ v2h pk(float a, float b) {
    union { f16x2 i; v2h o; } u;
    u.i = __builtin_amdgcn_cvt_pkrtz(a, b);
    return u.o;
}

#define MFMA32(a, b, c) __builtin_amdgcn_mfma_f32_16x16x32_f16((a), (b), (c), 0, 0, 0)
#define MFMA16(a, b, c) __builtin_amdgcn_mfma_f32_16x16x16f16((a), (b), (c), 0, 0, 0)

// Round 29: restore R27 (best verified kernel: 66.3-66.6us dispatch, clean
// traffic, VGPR 60). R28's produce-ahead (+26 live regs) spilled -- 4th
// confirmation that live state (48 acc + ~60 arch) is within ~20 regs of
// the 4-waves/SIMD unified-file ceiling; all added-state schemes spill.
// R27 = R25 col-packed structure (8pt x 2k in 16 cols, lane-linear LDS,
// conflict-free) + log2e folded into consume-side weights so exp is one
// v_exp_f32 (raw builtin; libm exp2f regressed) + fast-rcp sigmoid.
// Ledger: 3 different inner loops + 2 decompositions all land 66 +/- 1 us;
// combined issue ~77% (VALU 58 + MFMA 19); VALU-trim drops VALUBusy but
// not dur -> latency floor at reg-pinned 4 waves/SIMD.
__global__ __launch_bounds__(256, 4)
void gsl_mfma(const float* __restrict__ x,
              const float* __restrict__ trans_w, const float* __restrict__ trans_g,
              const float* __restrict__ trans_b, const float* __restrict__ trans_m,
              const float* __restrict__ trans_v,
              const float* __restrict__ pos_w1, const float* __restrict__ pos_g,
              const float* __restrict__ pos_b, const float* __restrict__ pos_m,
              const float* __restrict__ pos_v, const float* __restrict__ pos_w2,
              const float* __restrict__ pos_b2,
              const float* __restrict__ gate_w1, const float* __restrict__ gate_g,
              const float* __restrict__ gate_b, const float* __restrict__ gate_m,
              const float* __restrict__ gate_v, const float* __restrict__ gate_w2,
              const float* __restrict__ gate_b2,
              const float* __restrict__ attn_w1, const float* __restrict__ attn_g,
              const float* __restrict__ attn_b, const float* __restrict__ attn_m,
              const float* __restrict__ attn_v, const float* __restrict__ attn_w2,
              const float* __restrict__ attn_b2,
              float* __restrict__ out)
{
    __shared__ _Float16 WHL[1536];  // 6 sets x 64 lanes x v4h (lane-linear)
                                    // sets 0-3: WP1 mt, 4: WA1, 5: WG1
    __shared__ _Float16 W2L[4096];  // 8 tiles x 64 lanes x v8h (lane-linear)
    __shared__ float    PB2[64];

    const int tid  = threadIdx.x;
    const int wv   = tid >> 6;
    const int lane = tid & 63;
    const int p    = lane & 15;
    const int q    = lane >> 4;

    const int pt   = p & 7;     // point slot within wave
    const int ksub = p >> 3;    // k sub-slot: lane's k = 2g + ksub

    const int b  = blockIdx.x >> 8;                       // 2048 blocks
    const int nb = (blockIdx.x & 255) << 5;               // 32 points/block
    const int n  = nb | (wv << 3) | pt;

    // ---- stage pos_w2 K=32 A-frags into W2L (lane-linear, x LOG2E) ----
    // tile t = mt*2 + half; lane l=(qk*16+pp) elem j:
    //   A[m=pp][k=8qk+j] = LOG2E * W2[ch=(t>>1)*16+pp][ (t&1)*32 + h_local ]
    //   h_local = j<4 ? 4qk+j : 16 + 4qk + (j-4)   (concat-of-two-tiles map)
    #pragma unroll
    for (int e = 0; e < 16; ++e) {
        int idx = tid * 16 + e;              // 4096 elements
        int t   = idx >> 9;
        int rem = idx & 511;
        int l   = rem >> 3;
        int j   = rem & 7;
        int qk  = l >> 4;
        int pp  = l & 15;
        int hl  = (j < 4) ? (4 * qk + j) : (16 + 4 * qk + (j - 4));
        W2L[t * 512 + l * 8 + j] = (_Float16)(LOG2E *
            pos_w2[((t >> 1) * 16 + pp) * 64 + (t & 1) * 32 + hl]);
    }

    // ---- stage produce-side weight A-frags into WHL (UNSCALED) ----
    if (tid < 64) {
        const int c = tid;                   // pos hidden channel
        float sp = pos_g[c] * rsqrtf(pos_v[c] + EPSV);
        float bp = pos_b[c] - pos_m[c] * sp;
        const int mt = c >> 4, pp = c & 15;
        for (int k = 0; k < 16; ++k) {
            float v = (k >= 3 && k < 6) ? pos_w1[c * 3 + (k - 3)] * sp
                                        : ((k == 6) ? bp : 0.f);
            WHL[mt * 256 + ((k >> 2) * 16 + pp) * 4 + (k & 3)] = (_Float16)v;
        }
        PB2[c] = pos_b2[c] * LOG2E;
    } else if (tid < 80) {
        const int j = tid - 64;              // attn hidden channel
        float sa = attn_g[j] * rsqrtf(attn_v[j] + EPSV);
        float ba = attn_b[j] - attn_m[j] * sa;
        for (int k = 0; k < 16; ++k) {
            float v = (k < 6) ? attn_w1[j * 6 + k] * sa : ((k == 6) ? ba : 0.f);
            WHL[1024 + ((k >> 2) * 16 + j) * 4 + (k & 3)] = (_Float16)v;
        }
    } else if (tid < 96) {
        const int j = tid - 80;              // gate hidden channel
        float sg = gate_g[j] * rsqrtf(gate_v[j] + EPSV);
        float bg = gate_b[j] - gate_m[j] * sg;
        for (int k = 0; k < 16; ++k) {
            float v = (k < 6) ? gate_w1[j * 6 + k] * sg : ((k == 6) ? bg : 0.f);
            WHL[1280 + ((k >> 2) * 16 + j) * 4 + (k & 3)] = (_Float16)v;
        }
    }

    // ---- persistent A-frags (consume-side: x LOG2E) ----
    v4h WTf[4], WA2f[4], WG2f;
    #pragma unroll
    for (int mt = 0; mt < 4; ++mt) {
        const int ch = mt * 16 + p;
        #pragma unroll
        for (int i = 0; i < 4; ++i)
            WA2f[mt][i] = (_Float16)(LOG2E * attn_w2[ch * 16 + q * 4 + i]);
        float st = trans_g[ch] * rsqrtf(trans_v[ch] + EPSV);
        float bt = trans_b[ch] - trans_m[ch] * st;
        #pragma unroll
        for (int i = 0; i < 4; ++i) {
            int k = q * 4 + i;
            float v = (k < 6) ? trans_w[ch * 6 + k] * st : ((k == 6) ? bt : 0.f);
            WTf[mt][i] = (_Float16)(LOG2E * v);
        }
    }
    #pragma unroll
    for (int i = 0; i < 4; ++i)
        WG2f[i] = (_Float16)(LOG2E * gate_w2[4 * q + i]);
    const float gb2v = gate_b2[0] * LOG2E;

    __syncthreads();   // W2L/WHL/PB2 visible to all waves

    const _Float16* const WHLp = WHL + lane * 4;   // + set*256
    const _Float16* const W2Lp = W2L + lane * 8;   // + tile*512
    const float* const    PB2p = PB2 + 4 * q;      // + mt*16

    const v4f zero = {0.f, 0.f, 0.f, 0.f};
    v4f den[4], num[4], cmx[4];
    #pragma unroll
    for (int mt = 0; mt < 4; ++mt) {
        den[mt] = zero; num[mt] = zero;
        cmx[mt] = (v4f){-3.4e38f, -3.4e38f, -3.4e38f, -3.4e38f};
    }

    // ---- per-lane channel streams (only the 4 this lane consumes) ----
    const float* xb = x + ((size_t)(b * 6) * 8192 + n) * 20;
    const int hi = q & 1;   // q>=2 dups q&1 (A-side k>=8 rows are zero)
    const float* const s0p = xb + (size_t)(hi ? 4 : 0) * 163840;
    const float* const s1p = xb + (size_t)(hi ? 5 : 1) * 163840;
    const float* const s2p = xb + (size_t)(hi ? 4 : 2) * 163840;  // hi: L1 dup
    const float* const s3p = xb + (size_t)(hi ? 5 : 3) * 163840;  // hi: L1 dup

    // build v4h B-frag; hi lanes' high half is the constant (1.0, 0.0)
    auto mk = [&](float a, float bb, float cc, float dd) -> v4h {
        v2h lo = pk(a, bb);
        v2h hh = pk(cc, dd);
        if (hi) { union { unsigned u; v2h h; } t; t.u = 0x00003C00u; hh = t.h; }
        return (v4h){lo.x, lo.y, hh.x, hh.y};
    };

    // lane's k sequence: k = 2g + ksub, g = 0..9
    float c0 = s0p[ksub], c1 = s1p[ksub], c2 = s2p[ksub], c3 = s3p[ksub];

    #pragma unroll 1
    for (int g = 0; g < 10; ++g) {
        // prevent LICM from hoisting in-loop LDS reads into registers
        asm volatile("" ::: "memory");

        v4h xv = mk(c0, c1, c2, c3);
        if (g < 9) {
            const int kn = 2 * (g + 1) + ksub;
            c0 = s0p[kn]; c1 = s1p[kn]; c2 = s2p[kn]; c3 = s3p[kn];
        }

        // ---- hidden layers: packed outputs become K=32 B-frags directly ----
        union { v8h v; v4h h[2]; } uA, uC;   // tiles 0|1 and 2|3 concatenated
        #pragma unroll
        for (int mt = 0; mt < 4; ++mt) {
            v4f php = MFMA16(*(const v4h*)(WHLp + mt * 256), xv, zero);
            v2h e0 = lreluh2(pk(php[0], php[1]));
            v2h e1 = lreluh2(pk(php[2], php[3]));
            v4h pkd = (v4h){e0.x, e0.y, e1.x, e1.y};
            if (mt < 2) uA.h[mt] = pkd; else uC.h[mt - 2] = pkd;
        }
        v4f ahp = MFMA16(*(const v4h*)(WHLp + 1024), xv, zero);
        union { v4h v; v2h h[2]; } ua;
        ua.h[0] = lreluh2(pk(ahp[0], ahp[1]));
        ua.h[1] = lreluh2(pk(ahp[2], ahp[3]));
        const v4h ahB = ua.v;

        // gate: MFMA reduction (broadcast A); logit pre-scaled by LOG2E
        v4f ghp = MFMA16(*(const v4h*)(WHLp + 1280), xv, zero);
        union { v4h v; v2h h[2]; } ug;
        ug.h[0] = lreluh2(pk(ghp[0], ghp[1]));
        ug.h[1] = lreluh2(pk(ghp[2], ghp[3]));
        v4f gav = MFMA16(WG2f, ug.v, zero);
        const float gate =
            __builtin_amdgcn_rcpf(1.f + fexp2(-(gav[0] + gb2v)));

        // ---- consume: everything below is in s = log2e scale ----
        #pragma unroll
        for (int mt = 0; mt < 4; ++mt) {
            v8h w2a = *(const v8h*)(W2Lp + (mt * 2 + 0) * 512);  // h 0..31
            v8h w2b = *(const v8h*)(W2Lp + (mt * 2 + 1) * 512);  // h 32..63
            v4f pe = MFMA32(w2a, uA.v, *(const v4f*)(PB2p + mt * 16));
            pe = MFMA32(w2b, uC.v, pe);
            v4f tfa = MFMA16(WTf[mt], xv, zero);
            v4f tfv = lrelu4(tfa) + pe;          // = s * true tfv
            pe = MFMA16(WA2f[mt], ahB, pe);      // = s * true logits
            v4f e;
            #pragma unroll
            for (int r = 0; r < 4; ++r) e[r] = fexp2(pe[r]);   // 1x v_exp_f32
            den[mt] += e;
            num[mt] += tfv * e;
            cmx[mt] = __builtin_elementwise_max(cmx[mt], tfv * gate);
        }
    }

    // ---- combine the two k sub-slots (lanes differing in bit 3 of p) ----
    #pragma unroll
    for (int mt = 0; mt < 4; ++mt) {
        #pragma unroll
        for (int r = 0; r < 4; ++r) {
            den[mt][r] += __shfl_xor(den[mt][r], 8);
            num[mt][r] += __shfl_xor(num[mt][r], 8);
            cmx[mt][r] = fmaxf(cmx[mt][r], __shfl_xor(cmx[mt][r], 8));
        }
    }

    // write out (unscale by ln2): ksub==0 lanes own ch mt*16+4q+r, point n
    if ((lane & 8) == 0) {
        #pragma unroll
        for (int mt = 0; mt < 4; ++mt) {
            #pragma unroll
            for (int r = 0; r < 4; ++r) {
                const int ch = mt * 16 + 4 * q + r;
                out[((size_t)(b * 64 + ch)) * 8192 + n] =
                    (num[mt][r] / den[mt][r] + cmx[mt][r]) * LN2;
            }
        }
    }
}

extern "C" void kernel_launch(void* const* d_in, const int* in_sizes, int n_in,
                              void* d_out, int out_size, void* d_ws, size_t ws_size,
                              hipStream_t stream) {
    const float* x       = (const float*)d_in[0];
    const float* trans_w = (const float*)d_in[1];
    const float* trans_g = (const float*)d_in[2];
    const float* trans_b = (const float*)d_in[3];
    const float* trans_m = (const float*)d_in[4];
    const float* trans_v = (const float*)d_in[5];
    const float* pos_w1  = (const float*)d_in[6];
    const float* pos_g   = (const float*)d_in[7];
    const float* pos_b   = (const float*)d_in[8];
    const float* pos_m   = (const float*)d_in[9];
    const float* pos_v   = (const float*)d_in[10];
    const float* pos_w2  = (const float*)d_in[11];
    const float* pos_b2  = (const float*)d_in[12];
    const float* gate_w1 = (const float*)d_in[13];
    const float* gate_g  = (const float*)d_in[14];
    const float* gate_b  = (const float*)d_in[15];
    const float* gate_m  = (const float*)d_in[16];
    const float* gate_v  = (const float*)d_in[17];
    const float* gate_w2 = (const float*)d_in[18];
    const float* gate_b2 = (const float*)d_in[19];
    const float* attn_w1 = (const float*)d_in[20];
    const float* attn_g  = (const float*)d_in[21];
    const float* attn_b  = (const float*)d_in[22];
    const float* attn_m  = (const float*)d_in[23];
    const float* attn_v  = (const float*)d_in[24];
    const float* attn_w2 = (const float*)d_in[25];
    const float* attn_b2 = (const float*)d_in[26];
    float* out = (float*)d_out;

    // 8 b * 256 blocks/b; block = 4 waves x (8 points x 2 k-slots)
    gsl_mfma<<<2048, 256, 0, stream>>>(
        x, trans_w, trans_g, trans_b, trans_m, trans_v,
        pos_w1, pos_g, pos_b, pos_m, pos_v, pos_w2, pos_b2,
        gate_w1, gate_g, gate_b, gate_m, gate_v, gate_w2, gate_b2,
        attn_w1, attn_g, attn_b, attn_m, attn_v, attn_w2, attn_b2,
        out);
}